// Round 8
// baseline (255.296 us; speedup 1.0000x reference)
//
#include <hip/hip_runtime.h>
#include <hip/hip_bf16.h>

#define L 512
#define CS 256
#define CZ 128
#define LN_EPS 1e-5f

typedef _Float16 f16_t;
typedef f16_t f16x8 __attribute__((ext_vector_type(8)));
typedef float f32x4 __attribute__((ext_vector_type(4)));

#define PIN4(x) asm volatile("" : "+v"(reinterpret_cast<f32x4&>(x)))

// ---- Kernel PREP -----------------------------------------------------------
// Per-block (i = blockIdx.x): embed + LN -> s_out, u2 (CHUNK-MAJOR f16:
// u2[c>>3][i][c&7]), zrow = u@W1 + b, zcol = u@W2.
// Spare duties: blocks 0..127 build w3c (chunk-major W3^T f16), blocks
// 128..391 build tab[cp*66+rp] = Ecp[cp] + Erp[rp].
__global__ __launch_bounds__(256) void k_prep(
    const int* __restrict__ seq, const int* __restrict__ cid,
    const int* __restrict__ ridx,
    const float* __restrict__ Eaa, const float* __restrict__ Epos,
    const float* __restrict__ Ech, const float* __restrict__ lnw,
    const float* __restrict__ lnb, const float* __restrict__ Wp,
    const float* __restrict__ bp, const float* __restrict__ Ecp,
    const float* __restrict__ Erp,
    float* __restrict__ s_out, f16_t* __restrict__ u2,
    float* __restrict__ zrow, float* __restrict__ zcol,
    f16_t* __restrict__ w3c, float* __restrict__ tab)
{
    __shared__ float su[CS];
    __shared__ float red[8];
    const int i = blockIdx.x;
    const int c = threadIdx.x;

    if (i < 128) {
        w3c[(c >> 3) * (CZ * 8) + i * 8 + (c & 7)] = (f16_t)Wp[(2 * CS + c) * CZ + i];
    } else if (i < 128 + 264) {
        const int b2 = i - 128;
        if (c < CZ)
            tab[b2 * CZ + c] = Ecp[(b2 / 66) * CZ + c] + Erp[(b2 % 66) * CZ + c];
    }

    const int sq = seq[i], ri = ridx[i], ci = cid[i];
    const float v = Eaa[sq * CS + c] + Epos[ri * CS + c] + Ech[ci * CS + c];
    s_out[i * CS + c] = v;

    float s1 = v, s2 = v * v;
    #pragma unroll
    for (int o = 32; o > 0; o >>= 1) {
        s1 += __shfl_down(s1, o, 64);
        s2 += __shfl_down(s2, o, 64);
    }
    const int wv = c >> 6, lane = c & 63;
    if (lane == 0) { red[wv * 2] = s1; red[wv * 2 + 1] = s2; }
    __syncthreads();
    const float S  = red[0] + red[2] + red[4] + red[6];
    const float SS = red[1] + red[3] + red[5] + red[7];
    const float mu  = S * (1.0f / CS);
    const float var = SS * (1.0f / CS) - mu * mu;
    const float rs  = rsqrtf(var + LN_EPS);
    const float u   = (v - mu) * rs * lnw[c] + lnb[c];
    u2[(c >> 3) * (L * 8) + i * 8 + (c & 7)] = (f16_t)u;
    su[c] = u;
    __syncthreads();

    const int z = c & 127;
    const int half = c >> 7;  // 0 -> zrow(W1), 1 -> zcol(W2)
    const float* W = Wp + half * CS * CZ + z;
    float a0 = 0, a1 = 0, a2 = 0, a3 = 0;
    #pragma unroll 8
    for (int cc = 0; cc < CS; cc += 4) {
        a0 += su[cc + 0] * W[(cc + 0) * CZ];
        a1 += su[cc + 1] * W[(cc + 1) * CZ];
        a2 += su[cc + 2] * W[(cc + 2) * CZ];
        a3 += su[cc + 3] * W[(cc + 3) * CZ];
    }
    const float acc = (a0 + a1) + (a2 + a3);
    if (half) zcol[i * CZ + z] = acc;
    else      zrow[i * CZ + z] = acc + bp[z];
}

// ---- Kernel PAIR (v9: full z-row per wave — no cross-wave line assembly) ---
// Pattern across all failures (v6 WRITE 2.4x, v7 1.45x + FETCH 0.8x,
// v8 ~59us): some output cache line is assembled by >1 wave (64B halves in
// v6; 256B-granule halves split across waves 0/1 in v7; unbounded wave
// drift with zero barriers in v8) -> line evicted between partial writes ->
// RMW readback + double write. v9 removes the failure class: each wave owns
// the ENTIRE 512B z-row of its (i,j) pairs, written by 8 consecutive 16B
// stores of ONE wave. No line at ANY granularity (64/128/256/512B) has two
// writers. Structure:
//   block = 8 waves, tile 32j x 8i, grid (16,64); wave = 2i x 16j x 128z
//   (jh = w&1 -> 16 j's; iw = w>>1 -> i-pair)
//   - B = ui (x) uj built ONCE per wave (8 k-chunks x 2 i = 64 VGPR,
//     asm-pinned vs re-sinking), reused across all 8 z-tiles: kills R0's
//     8x z-redundancy (ds_reads ~24/wave total, conflict-free layout)
//   - A (W3^T) from L2 in an A_a/A_b ping-pong: ~16 MFMAs cover each
//     load's ~200cy L2 latency; w3c 64KB is L2-resident
//   - acc[2i][8zt] C-init = zrow+zcol+tab (proven v5-v8), loads issued
//     PRE-barrier to hide under LDS staging drain
//   - epilogue: 16 consecutive store insts per wave = 2 full rows,
//     16KB near-contiguous, single-writer
// VGPR ~220 at (512,2) -> 1 block/CU, 2 waves/SIMD; stores backpressure at
// the HBM drain rate (that IS the 22us floor), compute ~2us fits under.
__global__ __launch_bounds__(512, 2) void k_pair(
    const f16_t* __restrict__ u2, const f16_t* __restrict__ w3c,
    const float* __restrict__ zrow, const float* __restrict__ zcol,
    const float* __restrict__ tab,
    const int* __restrict__ cid, const int* __restrict__ ridx,
    float* __restrict__ zout)
{
    __shared__ f16_t lds[(1024 + 256) * 8];  // u_j tile (16KB) + u_i tile (4KB)
    f16x8* lj = (f16x8*)lds;
    f16x8* li = ((f16x8*)lds) + 1024;

    const int t = threadIdx.x;
    const int lane = t & 63, wave = t >> 6;
    const int m = lane & 15, q = lane >> 4;
    const int j0 = blockIdx.x * 32, i0 = blockIdx.y * 8;
    const int jh = wave & 1;              // 16 j's
    const int iw = wave >> 1;             // i-pair index [0,4)
    const int jm = j0 + jh * 16 + m;
    const int ia = i0 + iw * 2, ib = ia + 1;

    const f16x8* pu = (const f16x8*)u2;   // [32 chunks][512 rows]
    const f16x8* pw = (const f16x8*)w3c;  // [32 chunks][128 z]

    // stage LDS tiles (contiguous src + dst; measured conflict-free)
    if (t < 256) li[t] = pu[(t >> 3) * L + i0 + (t & 7)];   // t = ch*8 + ii
    #pragma unroll
    for (int rep = 0; rep < 2; ++rep) {
        const int un = rep * 512 + t;                       // un = ch*32 + jj
        lj[un] = pu[(un >> 5) * L + j0 + (un & 31)];
    }

    // ---- C-init: acc[i][zt] = zrow + zcol + tab, loads PRE-barrier -------
    const int cj = cid[jm], rj = ridx[jm];
    const int cia = cid[ia], ria = ridx[ia];
    const int cib = cid[ib], rib = ridx[ib];
    int d;
    d = ria - rj; d = d < -32 ? -32 : (d > 32 ? 32 : d);
    const int xa = ((cia * 2 + cj) * 66) + ((cia == cj) ? (d + 32) : 65);
    d = rib - rj; d = d < -32 ? -32 : (d > 32 ? 32 : d);
    const int xb = ((cib * 2 + cj) * 66) + ((cib == cj) ? (d + 32) : 65);

    f32x4 acc[2][8];
    #pragma unroll
    for (int zt = 0; zt < 8; ++zt) {
        const int zq = zt * 16 + q * 4;
        const f32x4 ZC = *(const f32x4*)&zcol[jm * CZ + zq];
        acc[0][zt] = *(const f32x4*)&zrow[ia * CZ + zq] + ZC
                   + *(const f32x4*)&tab[xa * CZ + zq];
        acc[1][zt] = *(const f32x4*)&zrow[ib * CZ + zq] + ZC
                   + *(const f32x4*)&tab[xb * CZ + zq];
    }

    __syncthreads();

    // ---- B fragments: built once, pinned, reused by all 8 z-tiles --------
    f16x8 B0[8], B1[8];
    #pragma unroll
    for (int k = 0; k < 8; ++k) {
        const int cb = k * 4 + q;
        const f16x8 uj  = lj[cb * 32 + jh * 16 + m];   // conflict-free b128
        B0[k] = li[cb * 8 + iw * 2]     * uj;          // broadcast reads
        B1[k] = li[cb * 8 + iw * 2 + 1] * uj;
    }
    #pragma unroll
    for (int k = 0; k < 8; ++k) { PIN4(B0[k]); PIN4(B1[k]); }

    // ---- zt loop: A ping-pong (A_a even tiles, A_b odd), L2 pipelined ----
    f16x8 A_a[8], A_b[8];
    #pragma unroll
    for (int k = 0; k < 8; ++k)                    // prefetch zt=0
        A_a[k] = pw[(k * 4 + q) * CZ + 0 * 16 + m];

    #pragma unroll 1
    for (int zp = 0; zp < 4; ++zp) {
        const int zt0 = zp * 2, zt1 = zt0 + 1;
        #pragma unroll
        for (int k = 0; k < 8; ++k)                // prefetch odd tile
            A_b[k] = pw[(k * 4 + q) * CZ + zt1 * 16 + m];
        #pragma unroll
        for (int k = 0; k < 8; ++k) {              // compute even tile
            acc[0][zt0] = __builtin_amdgcn_mfma_f32_16x16x32_f16(A_a[k], B0[k], acc[0][zt0], 0, 0, 0);
            acc[1][zt0] = __builtin_amdgcn_mfma_f32_16x16x32_f16(A_a[k], B1[k], acc[1][zt0], 0, 0, 0);
        }
        if (zp < 3) {
            #pragma unroll
            for (int k = 0; k < 8; ++k)            // prefetch next even
                A_a[k] = pw[(k * 4 + q) * CZ + (zt0 + 2) * 16 + m];
        }
        #pragma unroll
        for (int k = 0; k < 8; ++k) {              // compute odd tile
            acc[0][zt1] = __builtin_amdgcn_mfma_f32_16x16x32_f16(A_b[k], B0[k], acc[0][zt1], 0, 0, 0);
            acc[1][zt1] = __builtin_amdgcn_mfma_f32_16x16x32_f16(A_b[k], B1[k], acc[1][zt1], 0, 0, 0);
        }
    }

    // ---- epilogue: 2 full 512B rows, 8 consecutive 16B stores each -------
    {
        float* ra = zout + ((size_t)ia * L + jm) * CZ + q * 4;
        float* rb = zout + ((size_t)ib * L + jm) * CZ + q * 4;
        #pragma unroll
        for (int zt = 0; zt < 8; ++zt) *(f32x4*)(ra + zt * 16) = acc[0][zt];
        #pragma unroll
        for (int zt = 0; zt < 8; ++zt) *(f32x4*)(rb + zt * 16) = acc[1][zt];
    }
}

extern "C" void kernel_launch(void* const* d_in, const int* in_sizes, int n_in,
                              void* d_out, int out_size, void* d_ws, size_t ws_size,
                              hipStream_t stream) {
    const int*   seq  = (const int*)d_in[0];
    const int*   cid  = (const int*)d_in[1];
    const int*   ridx = (const int*)d_in[2];
    const float* Eaa  = (const float*)d_in[3];
    const float* Epos = (const float*)d_in[4];
    const float* Ech  = (const float*)d_in[5];
    const float* Ecp  = (const float*)d_in[6];
    const float* Erp  = (const float*)d_in[7];
    const float* Wp   = (const float*)d_in[8];
    const float* bp   = (const float*)d_in[9];
    const float* lnw  = (const float*)d_in[10];
    const float* lnb  = (const float*)d_in[11];

    float* out   = (float*)d_out;
    float* s_out = out;
    float* zout  = out + L * CS;

    char* ws = (char*)d_ws;
    f16_t* u2   = (f16_t*)ws;                 // 256 KB, chunk-major
    f16_t* w3c  = (f16_t*)(ws + 262144);      // 64 KB, chunk-major
    float* zrow = (float*)(ws + 327680);      // 256 KB
    float* zcol = (float*)(ws + 589824);      // 256 KB
    float* tab  = (float*)(ws + 851968);      // 132 KB

    hipLaunchKernelGGL(k_prep, dim3(L), dim3(256), 0, stream,
                       seq, cid, ridx, Eaa, Epos, Ech, lnw, lnb, Wp, bp,
                       Ecp, Erp, s_out, u2, zrow, zcol, w3c, tab);
    hipLaunchKernelGGL(k_pair, dim3(16, 64), dim3(512), 0, stream,
                       u2, w3c, zrow, zcol, tab, cid, ridx, zout);
}